// Round 6
// baseline (248.482 us; speedup 1.0000x reference)
//
#include <hip/hip_runtime.h>

// FlyHash-style sparse projection + per-row exact top-k threshold.
//
// Round 18: chunked double-buffer, engineered against BOTH failure modes
// measured in R15/R16:
//  - R16 failure 1: __syncthreads between chunks emits s_waitcnt vmcnt(0)
//    -> chunk-1 store drain on critical path. Fix: inter-chunk barrier is
//    raw s_barrier + lgkmcnt(0) only (the only cross-thread deps at that
//    point are LDS: in4b staging writes, hist clear, sh resets).
//  - vmcnt FIFO poison: any load issued AFTER the 40 stores whose data is
//    consumed waits on the whole store queue. Fix: chunk-2's staging loads
//    AND packed prefetch (rk2) issue BEFORE chunk-1's stores; their waits
//    then leave stores outstanding (vmcnt counts only newer entries).
//  - R16 failure 2: spills (VGPR 64 + 350MB scratch). Fix: straight-line
//    two-chunk body, disjoint register lifetimes (rk1 dead before rk2;
//    x4a dead at stores), peak ~100 VGPR < 128 cap at (1024,4).
// Per-chunk phases 1-4 are champion-R12 verbatim (prefetched rk = R17,
// measured 237.1 = best). Bit-exactness (absmax 0, R2-R17): serial f32
// fold-left ascending == ref einsum; threshold = actual x bit pattern.

typedef float f4 __attribute__((ext_vector_type(4)));

constexpr int IN_F   = 512;
constexpr int OUT_F  = 10240;
constexpr int TPB    = 1024;
constexpr int ROWS   = 4;                 // batch rows per chunk
constexpr int CHUNKS = 2;                 // chunks per block
constexpr int FPT    = OUT_F / TPB;       // 10 features per thread
constexpr int NBINS  = 1024;              // per-row bins over [4,6), width 1/512
constexpr int NWAVES = TPB / 64;          // 16
constexpr int CAP    = 64;                // bracket-bin list capacity per row

static_assert(NBINS == 64 * 16, "wave scan assumes 16 bins per lane");

// ---------------------------------------------------------------------------
// Kernel 1: extract sparse indices from dense W. One wave per W row.
// Emits indices ASCENDING (required for bit-exact fold-left downstream).
// ---------------------------------------------------------------------------
__global__ __launch_bounds__(256) void extract_idx(const float* __restrict__ W,
                                                   uint4* __restrict__ packed,
                                                   int out_f) {
  int row  = blockIdx.x * 4 + (threadIdx.x >> 6);
  int lane = threadIdx.x & 63;
  if (row >= out_f) return;

  const float* wr = W + (size_t)row * IN_F;
  unsigned long long masks[8];
#pragma unroll
  for (int c = 0; c < 8; ++c) {
    float v = wr[c * 64 + lane];
    masks[c] = __ballot(v != 0.0f);   // entries are exactly 0.0 or 1.0
  }
  if (lane == 0) {
    unsigned idx[6] = {IN_F, IN_F, IN_F, IN_F, IN_F, IN_F};  // pad -> zero slot
    int n = 0;
#pragma unroll
    for (int c = 0; c < 8; ++c) {
      unsigned long long m = masks[c];
      while (m && n < 6) {
        int b = __builtin_ctzll(m);
        idx[n++] = (unsigned)(c * 64 + b);
        m &= m - 1;
      }
    }
    uint4 r;
    r.x = idx[0] | (idx[1] << 16);
    r.y = idx[2] | (idx[3] << 16);
    r.z = idx[4] | (idx[5] << 16);
    r.w = (unsigned)n;
    packed[row] = r;
  }
}

// Serial fold of one row-component r (bit-identical to phase-1's fold).
__device__ __forceinline__ float row_val(const f4* in4, uint4 p, int r) {
  const float* b = (const float*)in4;
  float s = b[(p.x & 0xFFFFu) * 4 + r];
  s += b[(p.x >> 16) * 4 + r];
  s += b[(p.y & 0xFFFFu) * 4 + r];
  s += b[(p.y >> 16) * 4 + r];
  s += b[(p.z & 0xFFFFu) * 4 + r];
  s += b[(p.z >> 16) * 4 + r];
  return s;
}

// 4 strided input loads for the transposed LDS staging (caller guards tid).
__device__ __forceinline__ f4 stage_load(const float* __restrict__ inp,
                                         int row0, int tid) {
  const float* p = inp + (size_t)row0 * IN_F + tid;
  f4 v;
  v.x = p[0];
  v.y = p[IN_F];
  v.z = p[2 * IN_F];
  v.w = p[3 * IN_F];
  return v;
}

// ---------------------------------------------------------------------------
// Phases 1-4 for one chunk (champion-R12 verbatim, rk prefetched).
// On return sh_thr[0..3] holds the exact per-row thresholds and x4[] the
// per-thread row values.
// ---------------------------------------------------------------------------
__device__ __forceinline__ void compute_chunk(
    const f4* __restrict__ in4, const uint4* __restrict__ rk,
    const uint4* __restrict__ packed, int k, int tid, int lane, int wid,
    int* __restrict__ hist, int* __restrict__ wsum,
    int* __restrict__ sh_bstar, int* __restrict__ sh_above,
    int* __restrict__ sh_n, int* __restrict__ sh_cnt,
    float (*__restrict__ sh_list)[CAP], float* __restrict__ sh_thr,
    int* __restrict__ sh_need, f4* __restrict__ x4) {
  // --- phase 1: compute x (bit-exact serial fold-left) + histogram -------
#pragma unroll
  for (int i = 0; i < FPT; ++i) {
    uint4 r = rk[i];
    f4 s = in4[r.x & 0xFFFFu];          // ds_read_b128: 4 rows per gather
    s += in4[r.x >> 16];
    s += in4[r.y & 0xFFFFu];
    s += in4[r.y >> 16];
    s += in4[r.z & 0xFFFFu];
    s += in4[r.z >> 16];
    x4[i] = s;
#pragma unroll
    for (int rr = 0; rr < ROWS; ++rr) {
      float v = s[rr];
      if (v >= 4.0f) {                  // top-32 of 10240 ~ 4.8; bin >=4 only
        int b = (int)((v - 4.0f) * 512.0f);    // EXACT key (Sterbenz + pow2)
        b = b > NBINS - 1 ? NBINS - 1 : b;
        atomicAdd(&hist[rr * NBINS + b], 1);
      }
    }
  }
  __syncthreads();

  // --- phase 2: wave-parallel bracket-bin search (wave r owns row r) -----
  if (wid < ROWS) {
    const int r = wid;
    const int base = r * NBINS + lane * 16;
    int csum = 0;
#pragma unroll
    for (int j = 0; j < 16; ++j) csum += hist[base + j];
    int s = csum;                       // inclusive suffix sum across lanes
#pragma unroll
    for (int off = 1; off < 64; off <<= 1) {
      int t = __shfl_down(s, off);
      if (lane + off < 64) s += t;
    }
    int s_next = __shfl_down(s, 1);     // suffix starting at lane+1
    if (lane == 63) s_next = 0;
    if (s >= k && s_next < k) {         // unique crossing chunk (if any)
      int acc = s_next;
      int bsel = lane * 16, abv = s_next;
      for (int b = lane * 16 + 15; b >= lane * 16; --b) {
        int h = hist[r * NBINS + b];
        if (acc + h >= k) { bsel = b; abv = acc; break; }
        acc += h;
      }
      sh_bstar[r] = bsel;
      sh_above[r] = abv;
      sh_n[r]     = hist[r * NBINS + bsel];
    }
  }
  __syncthreads();

  // --- phase 3a: collect bracket-bin members into per-row lists ----------
  {
    const int b0 = sh_bstar[0], b1 = sh_bstar[1];
    const int b2 = sh_bstar[2], b3 = sh_bstar[3];
#pragma unroll
    for (int i = 0; i < FPT; ++i) {
      f4 s = x4[i];
#pragma unroll
      for (int rr = 0; rr < ROWS; ++rr) {
        float v = s[rr];
        int bb = (rr == 0) ? b0 : (rr == 1) ? b1 : (rr == 2) ? b2 : b3;
        if (v >= 4.0f) {
          int b = (int)((v - 4.0f) * 512.0f);
          b = b > NBINS - 1 ? NBINS - 1 : b;
          if (b == bb) {
            int p = atomicAdd(&sh_cnt[rr], 1);
            if (p < CAP) sh_list[rr][p] = v;
          }
        }
      }
    }
  }
  __syncthreads();

  // --- phase 3b: wave r rank-selects the (k-above)-th largest ------------
  if (wid < ROWS) {
    const int r   = wid;
    const int bst = sh_bstar[r];
    const int n   = (bst >= 0) ? sh_n[r] : CAP + 1;
    if (bst >= 0 && n <= CAP && sh_cnt[r] <= CAP) {
      const int j = k - sh_above[r];            // 1 <= j <= n
      float vl = (lane < n) ? sh_list[r][lane] : -1.0f;
      int cgt = 0, cge = 0;
      for (int m = 0; m < n; ++m) {
        float u = sh_list[r][m];                // broadcast LDS read
        cgt += (u > vl);
        cge += (u >= vl);
      }
      if (lane < n && cgt < j && cge >= j) sh_thr[r] = vl;  // exact k-th bits
      if (lane == 0) sh_need[r] = 0;
    } else {
      if (lane == 0) sh_need[r] = 1;            // overflow / no bracket
    }
  }
  __syncthreads();

  // --- phase 4: fallback (recomputes from LDS, never touches x4; rare) ---
#pragma unroll 1
  for (int r = 0; r < ROWS; ++r) {
    if (!sh_need[r]) continue;
    unsigned lo = 0u, hi = __float_as_uint(8.0f);
    while (lo < hi) {
      unsigned mid = lo + ((hi - lo + 1u) >> 1);
      float fm = __uint_as_float(mid);
      int c = 0;
      for (int i = 0; i < FPT; ++i) {
        uint4 p = packed[tid + i * TPB];
        c += (int)__popcll(__ballot(row_val(in4, p, r) >= fm));
      }
      if (lane == 0) wsum[wid] = c;
      __syncthreads();
      int tot = 0;
#pragma unroll
      for (int w = 0; w < NWAVES; ++w) tot += wsum[w];
      if (tot >= k) lo = mid; else hi = mid - 1u;
      __syncthreads();
    }
    if (tid == 0) sh_thr[r] = __uint_as_float(lo);
    __syncthreads();
  }
}

// ---------------------------------------------------------------------------
// Kernel 2: 2 chunks of 4 batch rows per block, 1024 threads.
// ---------------------------------------------------------------------------
__global__ __launch_bounds__(TPB, 4) void fly_hash(const float* __restrict__ inp,
                                                   const uint4* __restrict__ packed,
                                                   const int* __restrict__ kptr,
                                                   float* __restrict__ out,
                                                   int grid) {
  __shared__ f4    in4a[IN_F + 1];      // 8.2 KB; [IN_F] = zero slot for pads
  __shared__ f4    in4b[IN_F + 1];      // 8.2 KB; chunk-2 double buffer
  __shared__ int   hist[ROWS * NBINS];  // 16 KB
  __shared__ int   wsum[NWAVES];
  __shared__ int   sh_bstar[ROWS], sh_above[ROWS], sh_n[ROWS], sh_cnt[ROWS];
  __shared__ float sh_list[ROWS][CAP];
  __shared__ float sh_thr[ROWS];
  __shared__ int   sh_need[ROWS];       // 1 -> fallback binary search

  const int tid  = threadIdx.x;
  const int lane = tid & 63;
  const int wid  = tid >> 6;
  const int k    = *kptr;               // hash_length (32)
  const int rowA = blockIdx.x * ROWS;
  const int rowB = (blockIdx.x + grid) * ROWS;

  // --- chunk 1 prologue: prefetch rk1 + stage in4a -----------------------
  uint4 rk1[FPT];
#pragma unroll
  for (int i = 0; i < FPT; ++i) rk1[i] = packed[tid + i * TPB];

  if (tid < IN_F) {
    in4a[tid] = stage_load(inp, rowA, tid);    // ds_write_b128
  } else if (tid == IN_F) {
    f4 z = {0.0f, 0.0f, 0.0f, 0.0f};
    in4a[IN_F] = z;
  }
  if (tid < ROWS) { sh_bstar[tid] = -1; sh_cnt[tid] = 0; }
  for (int i = tid; i < ROWS * NBINS; i += TPB) hist[i] = 0;
  __syncthreads();

  // --- chunk 1 compute ---------------------------------------------------
  f4 x4a[FPT];
  compute_chunk(in4a, rk1, packed, k, tid, lane, wid, hist, wsum, sh_bstar,
                sh_above, sh_n, sh_cnt, sh_list, sh_thr, sh_need, x4a);

  // --- tail: issue chunk-2 loads BEFORE chunk-1 stores (vmcnt FIFO) ------
  f4 sv2;
  if (tid < IN_F) sv2 = stage_load(inp, rowB, tid);
  uint4 rk2[FPT];
#pragma unroll
  for (int i = 0; i < FPT; ++i) rk2[i] = packed[tid + i * TPB];

  {
    const float tA0 = sh_thr[0];
    const float tA1 = sh_thr[1];
    const float tA2 = sh_thr[2];
    const float tA3 = sh_thr[3];
    float* o0 = out + (size_t)(rowA + 0) * OUT_F;
    float* o1 = out + (size_t)(rowA + 1) * OUT_F;
    float* o2 = out + (size_t)(rowA + 2) * OUT_F;
    float* o3 = out + (size_t)(rowA + 3) * OUT_F;
#pragma unroll
    for (int i = 0; i < FPT; ++i) {
      int f = tid + i * TPB;
      f4 v = x4a[i];
      __builtin_nontemporal_store((v.x >= tA0) ? v.x : 0.0f, &o0[f]);
      __builtin_nontemporal_store((v.y >= tA1) ? v.y : 0.0f, &o1[f]);
      __builtin_nontemporal_store((v.z >= tA2) ? v.z : 0.0f, &o2[f]);
      __builtin_nontemporal_store((v.w >= tA3) ? v.w : 0.0f, &o3[f]);
    }
  }

  // Stage chunk-2 LDS + reset select state + clear hist. All LDS-only.
  if (tid < IN_F) {
    in4b[tid] = sv2;                    // waits its loads; stores stay queued
  } else if (tid == IN_F) {
    f4 z = {0.0f, 0.0f, 0.0f, 0.0f};
    in4b[IN_F] = z;
  }
  if (tid < ROWS) { sh_bstar[tid] = -1; sh_cnt[tid] = 0; }
  for (int i = tid; i < ROWS * NBINS; i += TPB) hist[i] = 0;

  // Inter-chunk barrier WITHOUT vmcnt drain: only LDS deps exist here.
  asm volatile("s_waitcnt lgkmcnt(0)" ::: "memory");
  __builtin_amdgcn_s_barrier();

  // --- chunk 2 compute + stores ------------------------------------------
  f4 x4b[FPT];
  compute_chunk(in4b, rk2, packed, k, tid, lane, wid, hist, wsum, sh_bstar,
                sh_above, sh_n, sh_cnt, sh_list, sh_thr, sh_need, x4b);

  {
    const float tB0 = sh_thr[0];
    const float tB1 = sh_thr[1];
    const float tB2 = sh_thr[2];
    const float tB3 = sh_thr[3];
    float* o0 = out + (size_t)(rowB + 0) * OUT_F;
    float* o1 = out + (size_t)(rowB + 1) * OUT_F;
    float* o2 = out + (size_t)(rowB + 2) * OUT_F;
    float* o3 = out + (size_t)(rowB + 3) * OUT_F;
#pragma unroll
    for (int i = 0; i < FPT; ++i) {
      int f = tid + i * TPB;
      f4 v = x4b[i];
      __builtin_nontemporal_store((v.x >= tB0) ? v.x : 0.0f, &o0[f]);
      __builtin_nontemporal_store((v.y >= tB1) ? v.y : 0.0f, &o1[f]);
      __builtin_nontemporal_store((v.z >= tB2) ? v.z : 0.0f, &o2[f]);
      __builtin_nontemporal_store((v.w >= tB3) ? v.w : 0.0f, &o3[f]);
    }
  }
}

// ---------------------------------------------------------------------------
extern "C" void kernel_launch(void* const* d_in, const int* in_sizes, int n_in,
                              void* d_out, int out_size, void* d_ws, size_t ws_size,
                              hipStream_t stream) {
  const float* inp = (const float*)d_in[0];
  const float* W   = (const float*)d_in[1];
  const int* kptr  = (const int*)d_in[2];
  float* out       = (float*)d_out;

  const int batch = in_sizes[0] / IN_F;   // 4096
  const int out_f = in_sizes[1] / IN_F;   // 10240

  uint4* packed = (uint4*)d_ws;           // 10240 * 16 B = 160 KB scratch

  const int grid = batch / ROWS / CHUNKS; // 512

  hipLaunchKernelGGL(extract_idx, dim3((out_f + 3) / 4), dim3(256), 0, stream,
                     W, packed, out_f);
  hipLaunchKernelGGL(fly_hash, dim3(grid), dim3(TPB), 0, stream,
                     inp, packed, kptr, out, grid);
}